// Round 5
// baseline (172.869 us; speedup 1.0000x reference)
//
#include <hip/hip_runtime.h>

typedef _Float16 f16;
typedef _Float16 f16x2 __attribute__((ext_vector_type(2)));
typedef _Float16 f16x4 __attribute__((ext_vector_type(4)));
typedef _Float16 f16x8 __attribute__((ext_vector_type(8)));
typedef float    f32x4 __attribute__((ext_vector_type(4)));
typedef float    f32x16 __attribute__((ext_vector_type(16)));

constexpr int B_ = 2, H_ = 16, T_ = 2048, D_ = 64, R_ = 32, NT = 32;
constexpr int NROW = B_ * H_ * T_;   // 65536 (bh,t) rows
constexpr int MT128 = T_ / 128;      // 16 m-tiles of 128

__device__ __forceinline__ f32x4 mfma16(f16x8 a, f16x8 b, f32x4 c) {
  return __builtin_amdgcn_mfma_f32_16x16x32_f16(a, b, c, 0, 0, 0);
}
__device__ __forceinline__ f32x16 mfma32(f16x8 a, f16x8 b, f32x16 c) {
  return __builtin_amdgcn_mfma_f32_32x32x16_f16(a, b, c, 0, 0, 0);
}
__device__ __forceinline__ void ld_lds16(const void* g, void* l) {
  __builtin_amdgcn_global_load_lds(
      (const __attribute__((address_space(1))) unsigned int*)g,
      (__attribute__((address_space(3))) unsigned int*)l, 16, 0, 0);
}

// ---------------- Kernel A: MFMA projections, fully staged I/O (as R4) ----------------
__global__ __launch_bounds__(256) void proj_kernel(
    const float* __restrict__ q, const float* __restrict__ k, const float* __restrict__ v,
    const float* __restrict__ Wq, const float* __restrict__ Wk,
    const float* __restrict__ c1, const float* __restrict__ c2,
    f16* __restrict__ qlr, f16* __restrict__ klr, f16* __restrict__ vt)
{
  __shared__ f16   sv[64 * 65];
  __shared__ float sW[2][64 * 33];
  __shared__ f16   sO[2][64 * 40];

  const int tid = threadIdx.x, w = tid >> 6, lane = tid & 63;
  const int l15 = lane & 15, l4 = lane >> 4;
  const int bh = blockIdx.x >> 5, h = bh & (H_ - 1);
  const int t0 = (blockIdx.x & 31) * 64;

  const float* vb = v + ((size_t)bh * T_ + t0) * D_;
  float4 vld[4];
#pragma unroll
  for (int it = 0; it < 4; ++it) vld[it] = ((const float4*)vb)[it * 256 + tid];

  const int m = t0 + 16 * w + l15;
  const float* qr = q + ((size_t)bh * T_ + m) * D_;
  const float* kr = k + ((size_t)bh * T_ + m) * D_;
  f16x8 aq[2], ak[2];
#pragma unroll
  for (int kc = 0; kc < 2; ++kc) {
    float4 x0 = *(const float4*)(qr + kc * 32 + 8 * l4);
    float4 x1 = *(const float4*)(qr + kc * 32 + 8 * l4 + 4);
    float4 y0 = *(const float4*)(kr + kc * 32 + 8 * l4);
    float4 y1 = *(const float4*)(kr + kc * 32 + 8 * l4 + 4);
    f16x8 A, K;
    A[0]=(f16)x0.x; A[1]=(f16)x0.y; A[2]=(f16)x0.z; A[3]=(f16)x0.w;
    A[4]=(f16)x1.x; A[5]=(f16)x1.y; A[6]=(f16)x1.z; A[7]=(f16)x1.w;
    K[0]=(f16)y0.x; K[1]=(f16)y0.y; K[2]=(f16)y0.z; K[3]=(f16)y0.w;
    K[4]=(f16)y1.x; K[5]=(f16)y1.y; K[6]=(f16)y1.z; K[7]=(f16)y1.w;
    aq[kc] = A; ak[kc] = K;
  }
  const float* Wqh = Wq + (size_t)h * D_ * R_;
  const float* Wkh = Wk + (size_t)h * D_ * R_;
  float4 wq0 = ((const float4*)Wqh)[tid * 2], wq1 = ((const float4*)Wqh)[tid * 2 + 1];
  float4 wk0 = ((const float4*)Wkh)[tid * 2], wk1 = ((const float4*)Wkh)[tid * 2 + 1];

#pragma unroll
  for (int it = 0; it < 4; ++it) {
    const int i4 = it * 256 + tid, t = i4 >> 4, dq = (i4 & 15) * 4;
    sv[t * 65 + dq    ] = (f16)vld[it].x;
    sv[t * 65 + dq + 1] = (f16)vld[it].y;
    sv[t * 65 + dq + 2] = (f16)vld[it].z;
    sv[t * 65 + dq + 3] = (f16)vld[it].w;
  }
  {
    const int d = tid >> 2, r0 = (tid & 3) * 8;
    float* pq = &sW[0][d * 33 + r0];
    float* pk = &sW[1][d * 33 + r0];
    pq[0]=wq0.x; pq[1]=wq0.y; pq[2]=wq0.z; pq[3]=wq0.w;
    pq[4]=wq1.x; pq[5]=wq1.y; pq[6]=wq1.z; pq[7]=wq1.w;
    pk[0]=wk0.x; pk[1]=wk0.y; pk[2]=wk0.z; pk[3]=wk0.w;
    pk[4]=wk1.x; pk[5]=wk1.y; pk[6]=wk1.z; pk[7]=wk1.w;
  }
  __syncthreads();

  const f32x4 z4 = {0.f, 0.f, 0.f, 0.f};
#pragma unroll
  for (int nt = 0; nt < 2; ++nt) {
    const int r = 16 * nt + l15;
    f16x8 bq[2], bk[2];
#pragma unroll
    for (int kc = 0; kc < 2; ++kc)
#pragma unroll
      for (int j2 = 0; j2 < 8; ++j2) {
        const int d = kc * 32 + 8 * l4 + j2;
        bq[kc][j2] = (f16)sW[0][d * 33 + r];
        bk[kc][j2] = (f16)sW[1][d * 33 + r];
      }
    f32x4 accq = mfma16(aq[0], bq[0], z4); accq = mfma16(aq[1], bq[1], accq);
    f32x4 acck = mfma16(ak[0], bk[0], z4); acck = mfma16(ak[1], bk[1], acck);
    const float scl = c1[h * 4 + (r >> 3)] * c2[h * 8 + (r & 7)] *
                      (0.17677669529663687f * 1.4426950408889634f);
#pragma unroll
    for (int i = 0; i < 4; ++i) {
      const int row = 16 * w + 4 * l4 + i;
      sO[0][row * 40 + r] = (f16)(accq[i] * scl);
      sO[1][row * 40 + r] = (f16)acck[i];
    }
  }
  __syncthreads();

  {
    const int row = tid >> 2, seg = (tid & 3) * 8;
    const size_t g = ((size_t)bh * T_ + t0 + row) * R_ + seg;
    *(f16x8*)(qlr + g) = *(const f16x8*)&sO[0][row * 40 + seg];
    *(f16x8*)(klr + g) = *(const f16x8*)&sO[1][row * 40 + seg];
  }
#pragma unroll
  for (int it = 0; it < 8; ++it) {
    const int idx = it * 256 + tid, d = idx >> 5, t = (idx & 31) * 2;
    f16x2 pr; pr[0] = sv[t * 65 + d]; pr[1] = sv[(t + 1) * 65 + d];
    const int sw = ((((t >> 3) ^ (d & 7)) << 3) | (t & 7));
    *(f16x2*)(vt + ((size_t)bh * D_ + d) * T_ + t0 + sw) = pr;
  }
}

// ---------------- Kernel B: flash attention, 128-m blocks (64 m/wave) ----------------
// Block = 128 q-rows of one (b,h); 2 waves, wave w owns m in [m0+64w, m0+64w+64).
// Per 64-n chunk: S^T (16 mfma16), online softmax (state: 4 scalars/lane),
// P -> swizzled s_p[w][64m][64n], O^T += V^T @ P^T (16 mfma32, V-frags shared
// across both m-halves). n-split (NS) flash-decoding across blocks as before.
__global__ __launch_bounds__(128) void attn_kernel(
    const f16* __restrict__ qlr, const f16* __restrict__ klr,
    const f16* __restrict__ vt, f16* __restrict__ On, float2* __restrict__ ml,
    const int ns_shift)
{
  __shared__ __align__(16) f16 s_k[64 * 32];       // 4 KB  [n][r] (DMA dest)
  __shared__ __align__(16) f16 s_vt[64 * 64];      // 8 KB  [d][n] swizzled (DMA dest)
  __shared__ __align__(16) f16 s_p[2][64 * 64];    // 16 KB per-wave P^T, swizzled

  const int tid = threadIdx.x, w = tid >> 6, lane = tid & 63;
  const int l15 = lane & 15, l4 = lane >> 4, l31 = lane & 31, hh = lane >> 5;
  const int NS = 1 << ns_shift;
  const int bh = blockIdx.x & 31;
  const int rest = blockIdx.x >> 5;
  const int mt = (MT128 - 1) - (rest >> ns_shift);   // longest rows dispatch first
  const int s  = rest & (NS - 1);
  const int m0 = mt * 128;
  const int mw = m0 + 64 * w;                        // this wave's m base

  // persistent Q B-frags for 4 m-subtiles of 16
  f16x8 aq[4];
#pragma unroll
  for (int msub = 0; msub < 4; ++msub)
    aq[msub] = *(const f16x8*)(qlr + ((size_t)bh * T_ + mw + 16 * msub + l15) * R_ + 8 * l4);

  const f16* kb = klr + (size_t)bh * T_ * R_;
  const f16* vb = vt + (size_t)bh * D_ * T_;

  f32x16 oacc[2][2];   // [d-half][m-half]; C col = m-local(32) = l31
#pragma unroll
  for (int c = 0; c < 2; ++c)
#pragma unroll
    for (int mh = 0; mh < 2; ++mh)
#pragma unroll
      for (int e = 0; e < 16; ++e) oacc[c][mh][e] = 0.f;
  float mi[4] = {-1e30f, -1e30f, -1e30f, -1e30f};
  float li[4] = {0.f, 0.f, 0.f, 0.f};
  const f32x4 z4 = {0.f, 0.f, 0.f, 0.f};

  const int jmax = 2 * mt + 1;
  for (int j = s; j <= jmax; j += NS) {
    const int n0 = 64 * j;
    __syncthreads();   // prior chunk's LDS reads done
#pragma unroll
    for (int e = 0; e < 2; ++e)
      ld_lds16((const char*)kb + (size_t)n0 * 64 + (2 * w + e) * 1024 + lane * 16,
               (char*)s_k + (2 * w + e) * 1024);
#pragma unroll
    for (int e = 0; e < 4; ++e) {
      const int d0 = w * 32 + e * 8;
      ld_lds16((const char*)vb + ((size_t)(d0 + (lane >> 3)) * T_ + n0) * 2 + (lane & 7) * 16,
               (char*)s_vt + d0 * 128);
    }
    __syncthreads();

    if (n0 <= mw + 63) {   // wave-uniform: skip fully-masked chunk (w=0 tail)
      // ---- S^T: 4 akf reads serve 16 MFMAs ----
      f32x4 sc[4][4];
#pragma unroll
      for (int ns = 0; ns < 4; ++ns) {
        const f16x8 akf = *(const f16x8*)&s_k[(16 * ns + l15) * 32 + 8 * l4];
#pragma unroll
        for (int msub = 0; msub < 4; ++msub)
          sc[ns][msub] = mfma16(akf, aq[msub], z4);
      }
      // causal mask: diagonal chunk for this wave is n0 == mw
      if (n0 == mw) {
#pragma unroll
        for (int ns = 0; ns < 4; ++ns) {
          const int nb = 16 * ns + 4 * l4;
#pragma unroll
          for (int msub = 0; msub < 4; ++msub) {
            const int lim = 16 * msub + l15;
#pragma unroll
            for (int i = 0; i < 4; ++i)
              if (nb + i > lim) sc[ns][msub][i] = -1e30f;
          }
        }
      }

      // ---- online softmax per m-sub ----
      float mn[4], al[4], rs[4];
#pragma unroll
      for (int msub = 0; msub < 4; ++msub) {
        float rm = -1e30f;
#pragma unroll
        for (int ns = 0; ns < 4; ++ns)
#pragma unroll
          for (int i = 0; i < 4; ++i) rm = fmaxf(rm, sc[ns][msub][i]);
        rm = fmaxf(rm, __shfl_xor(rm, 16)); rm = fmaxf(rm, __shfl_xor(rm, 32));
        mn[msub] = fmaxf(mi[msub], rm);
        al[msub] = exp2f(mi[msub] - mn[msub]);
        rs[msub] = 0.f;
      }
#pragma unroll
      for (int ns = 0; ns < 4; ++ns) {
        const int col = ((((2 * ns + (l4 >> 1)) ^ (l15 & 7)) << 3) | (4 * (l4 & 1)));
#pragma unroll
        for (int msub = 0; msub < 4; ++msub) {
          f16x4 pv;
#pragma unroll
          for (int i = 0; i < 4; ++i) {
            const float p = exp2f(sc[ns][msub][i] - mn[msub]);
            rs[msub] += p;
            pv[i] = (f16)p;
          }
          *(f16x4*)&s_p[w][(16 * msub + l15) * 64 + col] = pv;
        }
      }
#pragma unroll
      for (int msub = 0; msub < 4; ++msub) {
        rs[msub] += __shfl_xor(rs[msub], 16);
        rs[msub] += __shfl_xor(rs[msub], 32);
        li[msub] = li[msub] * al[msub] + rs[msub];
        mi[msub] = mn[msub];
      }
      const float aPV0 = al[l4 & 1];        // m-col = l31 -> msub = 2*mh + (l4&1)
      const float aPV1 = al[2 + (l4 & 1)];
#pragma unroll
      for (int c = 0; c < 2; ++c) { oacc[c][0] *= aPV0; oacc[c][1] *= aPV1; }

      // ---- O^T += V^T @ P^T: 8 V-frag reads serve 16 MFMAs ----
#pragma unroll
      for (int kc = 0; kc < 4; ++kc) {
        const int u = (2 * kc + hh) ^ (l31 & 7);
        const f16x8 bp0 = *(const f16x8*)&s_p[w][l31 * 64 + u * 8];
        const f16x8 bp1 = *(const f16x8*)&s_p[w][(32 + l31) * 64 + u * 8];
#pragma unroll
        for (int c = 0; c < 2; ++c) {
          const f16x8 av = *(const f16x8*)&s_vt[(32 * c + l31) * 64 + u * 8];
          oacc[c][0] = mfma32(av, bp0, oacc[c][0]);
          oacc[c][1] = mfma32(av, bp1, oacc[c][1]);
        }
      }
    }
  }

  // ---- epilogue: normalized partial O (f16) + (m,l) ----
#pragma unroll
  for (int mh = 0; mh < 2; ++mh) {
    const float myl = li[2 * mh + (l4 & 1)];
    const float invl = myl > 0.f ? 1.f / myl : 0.f;
    f16* ob = On + (((size_t)s * 32 + bh) * T_ + mw + 32 * mh + l31) * D_;
#pragma unroll
    for (int c = 0; c < 2; ++c)
#pragma unroll
      for (int g = 0; g < 4; ++g) {
        f16x4 o;
#pragma unroll
        for (int e = 0; e < 4; ++e) o[e] = (f16)(oacc[c][mh][4 * g + e] * invl);
        *(f16x4*)(ob + 32 * c + 8 * g + 4 * hh) = o;
      }
  }
  {
    const float mm = (l4 & 2) ? ((l4 & 1) ? mi[3] : mi[2]) : ((l4 & 1) ? mi[1] : mi[0]);
    const float ll = (l4 & 2) ? ((l4 & 1) ? li[3] : li[2]) : ((l4 & 1) ? li[1] : li[0]);
    float2 mlv; mlv.x = mm; mlv.y = ll;
    ml[((size_t)s * 32 + bh) * T_ + mw + 16 * l4 + l15] = mlv;
  }
}

// ---------------- Kernel C: merge n-split partials ----------------
__global__ __launch_bounds__(256) void merge_kernel(
    const f16* __restrict__ On, const float2* __restrict__ ml,
    float* __restrict__ out, const int NS)
{
  const int row = blockIdx.x * 32 + (threadIdx.x >> 3);
  const int d0 = (threadIdx.x & 7) * 8;
  float res[8];
  if (NS == 1) {
    const f16x8 o0 = *(const f16x8*)(On + (size_t)row * 64 + d0);
#pragma unroll
    for (int e = 0; e < 8; ++e) res[e] = (float)o0[e];
  } else {
    float2 mls[4];
    float ms = -3e38f;
    for (int s = 0; s < NS; ++s) {
      mls[s] = ml[(size_t)s * NROW + row];
      ms = fmaxf(ms, mls[s].x);
    }
    float wt[4], wsum = 0.f;
    for (int s = 0; s < NS; ++s) {
      wt[s] = exp2f(mls[s].x - ms) * mls[s].y;
      wsum += wt[s];
    }
    const float inv = 1.f / wsum;
#pragma unroll
    for (int e = 0; e < 8; ++e) res[e] = 0.f;
    for (int s = 0; s < NS; ++s) {
      const f16x8 o = *(const f16x8*)(On + ((size_t)s * NROW + row) * 64 + d0);
      const float c = wt[s] * inv;
#pragma unroll
      for (int e = 0; e < 8; ++e) res[e] += c * (float)o[e];
    }
  }
  float* ob = out + (size_t)row * 64 + d0;
  f32x4 r0, r1;
#pragma unroll
  for (int e = 0; e < 4; ++e) { r0[e] = res[e]; r1[e] = res[4 + e]; }
  *(f32x4*)ob = r0;
  *(f32x4*)(ob + 4) = r1;
}

extern "C" void kernel_launch(void* const* d_in, const int* in_sizes, int n_in,
                              void* d_out, int out_size, void* d_ws, size_t ws_size,
                              hipStream_t stream) {
  const float* q  = (const float*)d_in[0];
  const float* k  = (const float*)d_in[1];
  const float* v  = (const float*)d_in[2];
  const float* Wq = (const float*)d_in[3];
  const float* Wk = (const float*)d_in[4];
  const float* c1 = (const float*)d_in[5];
  const float* c2 = (const float*)d_in[6];
  float* out = (float*)d_out;

  f16* qlr = (f16*)d_ws;                                   // 4 MiB
  f16* klr = qlr + (size_t)B_ * H_ * T_ * R_;              // 4 MiB
  f16* vt  = klr + (size_t)B_ * H_ * T_ * R_;              // 8 MiB
  f16* On  = vt + (size_t)B_ * H_ * T_ * D_;

  const size_t projB = (size_t)16 * 1024 * 1024;
  const size_t perSplit = (size_t)NROW * D_ * 2 + (size_t)NROW * 8;  // On + ml
  // NS=2 is the measured sweet spot (NS=4 regressed: per-block overhead + 2x On traffic)
  int ns_shift = 0;
  if (ws_size >= projB + 2 * perSplit) ns_shift = 1;
  const int NS = 1 << ns_shift;
  float2* ml = (float2*)(On + (size_t)NS * NROW * D_);

  proj_kernel<<<B_ * H_ * NT, 256, 0, stream>>>(q, k, v, Wq, Wk, c1, c2, qlr, klr, vt);
  attn_kernel<<<B_ * H_ * MT128 * NS, 128, 0, stream>>>(qlr, klr, vt, On, ml, ns_shift);
  merge_kernel<<<NROW / 32, 256, 0, stream>>>(On, ml, out, NS);
}

// Round 7
// 165.366 us; speedup vs baseline: 1.0454x; 1.0454x over previous
//
#include <hip/hip_runtime.h>

typedef _Float16 f16;
typedef _Float16 f16x2 __attribute__((ext_vector_type(2)));
typedef _Float16 f16x8 __attribute__((ext_vector_type(8)));
typedef float    f32x4 __attribute__((ext_vector_type(4)));
typedef float    f32x16 __attribute__((ext_vector_type(16)));
typedef unsigned int u32;

constexpr int B_ = 2, H_ = 16, T_ = 2048, D_ = 64, R_ = 32, NT = 32;
constexpr int MT = 16;               // 128-row m-tiles
constexpr int NROW = B_ * H_ * T_;   // 65536

__device__ __forceinline__ f32x4 mfma16(f16x8 a, f16x8 b, f32x4 c) {
  return __builtin_amdgcn_mfma_f32_16x16x32_f16(a, b, c, 0, 0, 0);
}
__device__ __forceinline__ f32x16 mfma32(f16x8 a, f16x8 b, f32x16 c) {
  return __builtin_amdgcn_mfma_f32_32x32x16_f16(a, b, c, 0, 0, 0);
}
__device__ __forceinline__ u32 pkrtz(float a, float b) {
  return __builtin_bit_cast(u32, __builtin_amdgcn_cvt_pkrtz(a, b));
}

// Workspace layouts (all f16), designed so attn frag-loads are contiguous:
//  qlr/klr: [bh][jt(32)][kc(2)][hh(2)][tl(64)][8]   (elem (t,r): jt=t>>6,tl=t&63,kc=r>>4,hh=(r>>3)&1,i=r&7)
//  vt:      [bh][jt(32)][u(8)][d(64)][8]            (elem (d,t): u=(t>>3)&7, i=t&7)

// ---------------- Kernel A: MFMA projections ----------------
__global__ __launch_bounds__(256) void proj_kernel(
    const float* __restrict__ q, const float* __restrict__ k, const float* __restrict__ v,
    const float* __restrict__ Wq, const float* __restrict__ Wk,
    const float* __restrict__ c1, const float* __restrict__ c2,
    f16* __restrict__ qlr, f16* __restrict__ klr, f16* __restrict__ vt)
{
  __shared__ f16   sv[64 * 65];
  __shared__ float sW[2][64 * 33];
  __shared__ f16   sO[2][64 * 40];

  const int tid = threadIdx.x, w = tid >> 6, lane = tid & 63;
  const int l15 = lane & 15, l4 = lane >> 4;
  const int bh = blockIdx.x >> 5, h = bh & (H_ - 1);
  const int jt = blockIdx.x & 31, t0 = jt * 64;

  const float* vb = v + ((size_t)bh * T_ + t0) * D_;
  float4 vld[4];
#pragma unroll
  for (int it = 0; it < 4; ++it) vld[it] = ((const float4*)vb)[it * 256 + tid];

  const int m = t0 + 16 * w + l15;
  const float* qr = q + ((size_t)bh * T_ + m) * D_;
  const float* kr = k + ((size_t)bh * T_ + m) * D_;
  f16x8 aq[2], ak[2];
#pragma unroll
  for (int kc = 0; kc < 2; ++kc) {
    float4 x0 = *(const float4*)(qr + kc * 32 + 8 * l4);
    float4 x1 = *(const float4*)(qr + kc * 32 + 8 * l4 + 4);
    float4 y0 = *(const float4*)(kr + kc * 32 + 8 * l4);
    float4 y1 = *(const float4*)(kr + kc * 32 + 8 * l4 + 4);
    f16x8 A, K;
    A[0]=(f16)x0.x; A[1]=(f16)x0.y; A[2]=(f16)x0.z; A[3]=(f16)x0.w;
    A[4]=(f16)x1.x; A[5]=(f16)x1.y; A[6]=(f16)x1.z; A[7]=(f16)x1.w;
    K[0]=(f16)y0.x; K[1]=(f16)y0.y; K[2]=(f16)y0.z; K[3]=(f16)y0.w;
    K[4]=(f16)y1.x; K[5]=(f16)y1.y; K[6]=(f16)y1.z; K[7]=(f16)y1.w;
    aq[kc] = A; ak[kc] = K;
  }
  const float* Wqh = Wq + (size_t)h * D_ * R_;
  const float* Wkh = Wk + (size_t)h * D_ * R_;
  float4 wq0 = ((const float4*)Wqh)[tid * 2], wq1 = ((const float4*)Wqh)[tid * 2 + 1];
  float4 wk0 = ((const float4*)Wkh)[tid * 2], wk1 = ((const float4*)Wkh)[tid * 2 + 1];

#pragma unroll
  for (int it = 0; it < 4; ++it) {
    const int i4 = it * 256 + tid, t = i4 >> 4, dq = (i4 & 15) * 4;
    sv[t * 65 + dq    ] = (f16)vld[it].x;
    sv[t * 65 + dq + 1] = (f16)vld[it].y;
    sv[t * 65 + dq + 2] = (f16)vld[it].z;
    sv[t * 65 + dq + 3] = (f16)vld[it].w;
  }
  {
    const int d = tid >> 2, r0 = (tid & 3) * 8;
    float* pq = &sW[0][d * 33 + r0];
    float* pk = &sW[1][d * 33 + r0];
    pq[0]=wq0.x; pq[1]=wq0.y; pq[2]=wq0.z; pq[3]=wq0.w;
    pq[4]=wq1.x; pq[5]=wq1.y; pq[6]=wq1.z; pq[7]=wq1.w;
    pk[0]=wk0.x; pk[1]=wk0.y; pk[2]=wk0.z; pk[3]=wk0.w;
    pk[4]=wk1.x; pk[5]=wk1.y; pk[6]=wk1.z; pk[7]=wk1.w;
  }
  __syncthreads();

  const f32x4 z4 = {0.f, 0.f, 0.f, 0.f};
#pragma unroll
  for (int nt = 0; nt < 2; ++nt) {
    const int r = 16 * nt + l15;
    f16x8 bq[2], bk[2];
#pragma unroll
    for (int kc = 0; kc < 2; ++kc)
#pragma unroll
      for (int j2 = 0; j2 < 8; ++j2) {
        const int d = kc * 32 + 8 * l4 + j2;
        bq[kc][j2] = (f16)sW[0][d * 33 + r];
        bk[kc][j2] = (f16)sW[1][d * 33 + r];
      }
    f32x4 accq = mfma16(aq[0], bq[0], z4); accq = mfma16(aq[1], bq[1], accq);
    f32x4 acck = mfma16(ak[0], bk[0], z4); acck = mfma16(ak[1], bk[1], acck);
    const float scl = c1[h * 4 + (r >> 3)] * c2[h * 8 + (r & 7)] *
                      (0.17677669529663687f * 1.4426950408889634f);
#pragma unroll
    for (int i = 0; i < 4; ++i) {
      const int row = 16 * w + 4 * l4 + i;
      sO[0][row * 40 + r] = (f16)(accq[i] * scl);
      sO[1][row * 40 + r] = (f16)acck[i];
    }
  }
  __syncthreads();

  // coalesced stores into fragment-order tiled layouts
  {
    const int row = tid >> 2, q4 = tid & 3;           // q4 = (kc<<1)|hh of r-segment
    const size_t base = ((((size_t)bh * 32 + jt) * 2 + (q4 >> 1)) * 2 + (q4 & 1)) * 64 + row;
    *(f16x8*)(qlr + base * 8) = *(const f16x8*)&sO[0][row * 40 + q4 * 8];
    *(f16x8*)(klr + base * 8) = *(const f16x8*)&sO[1][row * 40 + q4 * 8];
  }
#pragma unroll
  for (int it = 0; it < 8; ++it) {
    const int d = tid >> 2, i2 = (tid & 3) * 2, t = it * 8 + i2;
    f16x2 pr; pr[0] = sv[t * 65 + d]; pr[1] = sv[(t + 1) * 65 + d];
    *(f16x2*)(vt + (((size_t)bh * 32 + jt) * 8 + it) * 512 + d * 8 + i2) = pr;
  }
}

// ---------------- Kernel B: barrier-free, LDS-free flash attention ----------------
// 4 independent waves/block; wave w owns 32 m-cols (mw = 128*mt + 32w).
// Per 64-n chunk: S^T via 4 mfma32 (C col = m = lane&31 -> scalar softmax state),
// P transposed in-register (shfl_xor 32 quad swap), PV via 8 mfma32.
__global__ __launch_bounds__(256, 4) void attn_kernel(
    const f16* __restrict__ qlr, const f16* __restrict__ klr,
    const f16* __restrict__ vt, f16* __restrict__ On, float2* __restrict__ ml,
    const int ns_shift)
{
  const int tid = threadIdx.x, w = tid >> 6, lane = tid & 63;
  const int l31 = lane & 31, hh = lane >> 5;
  const int NS = 1 << ns_shift;
  const int bh = blockIdx.x & 31;
  const int rest = blockIdx.x >> 5;
  const int mt = (MT - 1) - (rest >> ns_shift);   // longest rows dispatch first
  const int s  = rest & (NS - 1);
  const int mw = mt * 128 + 32 * w;

  // persistent Q B-frags: B[k=r][col=m=l31]
  const int jm = mw >> 6, mloc = (mw & 63) + l31;
  const f16* qb = qlr + (((size_t)bh * 32 + jm) * 2048) + hh * 512 + (size_t)mloc * 8;
  const f16x8 bq0 = *(const f16x8*)(qb);
  const f16x8 bq1 = *(const f16x8*)(qb + 1024);

  const f16* kb = klr + (size_t)bh * 32 * 2048;
  const f16* vb = vt + (size_t)bh * 32 * 4096;

  f32x16 oacc[2];
  f32x16 z16;
#pragma unroll
  for (int e = 0; e < 16; ++e) { z16[e] = 0.f; oacc[0][e] = 0.f; oacc[1][e] = 0.f; }
  float mi = -1e30f, li = 0.f;

  const int jw = 2 * mt + (w >> 1);   // last chunk this wave needs
  for (int j = s; j <= jw; j += NS) {
    const f16* kj = kb + (size_t)j * 2048;
    const f16* vj = vb + (size_t)j * 4096;

    // ---- S^T[n][m]: A = K rows n, B = Q cols m ----
    f32x16 sc[2];
#pragma unroll
    for (int nt = 0; nt < 2; ++nt) {
      const int nl = 32 * nt + l31;
      const f16x8 a0 = *(const f16x8*)(kj + hh * 512 + nl * 8);
      const f16x8 a1 = *(const f16x8*)(kj + 1024 + hh * 512 + nl * 8);
      sc[nt] = mfma32(a0, bq0, z16);
      sc[nt] = mfma32(a1, bq1, sc[nt]);
    }
    // causal mask (each wave has exactly one straddling chunk)
    const int n0 = j * 64;
    if (n0 + 63 > mw) {
      const int lim = mw + l31 - n0;
#pragma unroll
      for (int nt = 0; nt < 2; ++nt)
#pragma unroll
        for (int e = 0; e < 16; ++e) {
          const int nv = 32 * nt + 4 * hh + (e & 3) + 8 * (e >> 2);
          if (nv > lim) sc[nt][e] = -1e30f;
        }
    }

    // ---- online softmax: col m = l31, scalar state; combine halves via 1 shfl ----
    float rm = -1e30f;
#pragma unroll
    for (int nt = 0; nt < 2; ++nt)
#pragma unroll
      for (int e = 0; e < 16; ++e) rm = fmaxf(rm, sc[nt][e]);
    rm = fmaxf(rm, __shfl_xor(rm, 32));
    const float mn = fmaxf(mi, rm);
    const float alpha = exp2f(mi - mn);
    float rs = 0.f;
    u32 pk[2][8];   // packed P pairs, in C/D element order
#pragma unroll
    for (int nt = 0; nt < 2; ++nt)
#pragma unroll
      for (int s4 = 0; s4 < 4; ++s4) {
        const float p0 = exp2f(sc[nt][4 * s4 + 0] - mn);
        const float p1 = exp2f(sc[nt][4 * s4 + 1] - mn);
        const float p2 = exp2f(sc[nt][4 * s4 + 2] - mn);
        const float p3 = exp2f(sc[nt][4 * s4 + 3] - mn);
        rs += (p0 + p1) + (p2 + p3);
        pk[nt][2 * s4]     = pkrtz(p0, p1);
        pk[nt][2 * s4 + 1] = pkrtz(p2, p3);
      }
    rs += __shfl_xor(rs, 32);
    li = li * alpha + rs; mi = mn;
#pragma unroll
    for (int c = 0; c < 2; ++c)
#pragma unroll
      for (int e = 0; e < 16; ++e) oacc[c][e] *= alpha;

    // ---- PV: in-register P transpose (quad swap with lane^32) + mfma32 ----
#pragma unroll
    for (int nt = 0; nt < 2; ++nt)
#pragma unroll
      for (int kcp = 0; kcp < 2; ++kcp) {
        const int kc = 2 * nt + kcp;
        const u32 sA = hh ? pk[nt][4 * kcp]     : pk[nt][4 * kcp + 2];
        const u32 sB = hh ? pk[nt][4 * kcp + 1] : pk[nt][4 * kcp + 3];
        const u32 kA = hh ? pk[nt][4 * kcp + 2] : pk[nt][4 * kcp];
        const u32 kB = hh ? pk[nt][4 * kcp + 3] : pk[nt][4 * kcp + 1];
        const u32 r0 = (u32)__shfl_xor((int)sA, 32);
        const u32 r1 = (u32)__shfl_xor((int)sB, 32);
        union { f16x8 v; u32 u[4]; } bp;
        bp.u[0] = hh ? r0 : kA;
        bp.u[1] = hh ? r1 : kB;
        bp.u[2] = hh ? kA : r0;
        bp.u[3] = hh ? kB : r1;
#pragma unroll
        for (int c = 0; c < 2; ++c) {
          const f16x8 av = *(const f16x8*)(vj + (size_t)(kc * 2 + hh) * 512 + (32 * c + l31) * 8);
          oacc[c] = mfma32(av, bp.v, oacc[c]);
        }
      }
  }

  // ---- epilogue: normalized partial O (f16) + (m,l) ----
  const float invl = li > 0.f ? 1.f / li : 0.f;
  f16* ob = On + (((size_t)s * 32 + bh) * T_ + mw + l31) * D_;
#pragma unroll
  for (int c = 0; c < 2; ++c)
#pragma unroll
    for (int s4 = 0; s4 < 4; ++s4) {
      const int d0 = 32 * c + 8 * s4 + 4 * hh;
      const u32 e0 = pkrtz(oacc[c][4 * s4] * invl, oacc[c][4 * s4 + 1] * invl);
      const u32 e1 = pkrtz(oacc[c][4 * s4 + 2] * invl, oacc[c][4 * s4 + 3] * invl);
      *(u32*)(ob + d0)     = e0;
      *(u32*)(ob + d0 + 2) = e1;
    }
  if (!hh) {
    float2 mlv; mlv.x = mi; mlv.y = li;
    ml[((size_t)s * 32 + bh) * T_ + mw + l31] = mlv;
  }
}

// ---------------- Kernel C: merge n-split partials ----------------
__global__ __launch_bounds__(256) void merge_kernel(
    const f16* __restrict__ On, const float2* __restrict__ ml,
    float* __restrict__ out, const int NS)
{
  const int row = blockIdx.x * 32 + (threadIdx.x >> 3);
  const int d0 = (threadIdx.x & 7) * 8;
  float res[8];
  if (NS == 1) {
    const f16x8 o0 = *(const f16x8*)(On + (size_t)row * 64 + d0);
#pragma unroll
    for (int e = 0; e < 8; ++e) res[e] = (float)o0[e];
  } else {
    float2 mls[4];
    float ms = -3e38f;
    for (int s = 0; s < NS; ++s) {
      mls[s] = ml[(size_t)s * NROW + row];
      ms = fmaxf(ms, mls[s].x);
    }
    float wt[4], wsum = 0.f;
    for (int s = 0; s < NS; ++s) {
      wt[s] = exp2f(mls[s].x - ms) * mls[s].y;
      wsum += wt[s];
    }
    const float inv = 1.f / wsum;
#pragma unroll
    for (int e = 0; e < 8; ++e) res[e] = 0.f;
    for (int s = 0; s < NS; ++s) {
      const f16x8 o = *(const f16x8*)(On + ((size_t)s * NROW + row) * 64 + d0);
      const float c = wt[s] * inv;
#pragma unroll
      for (int e = 0; e < 8; ++e) res[e] += c * (float)o[e];
    }
  }
  float* ob = out + (size_t)row * 64 + d0;
  f32x4 r0, r1;
#pragma unroll
  for (int e = 0; e < 4; ++e) { r0[e] = res[e]; r1[e] = res[4 + e]; }
  *(f32x4*)ob = r0;
  *(f32x4*)(ob + 4) = r1;
}

extern "C" void kernel_launch(void* const* d_in, const int* in_sizes, int n_in,
                              void* d_out, int out_size, void* d_ws, size_t ws_size,
                              hipStream_t stream) {
  const float* q  = (const float*)d_in[0];
  const float* k  = (const float*)d_in[1];
  const float* v  = (const float*)d_in[2];
  const float* Wq = (const float*)d_in[3];
  const float* Wk = (const float*)d_in[4];
  const float* c1 = (const float*)d_in[5];
  const float* c2 = (const float*)d_in[6];
  float* out = (float*)d_out;

  f16* qlr = (f16*)d_ws;                                   // 4 MiB
  f16* klr = qlr + (size_t)B_ * H_ * T_ * R_;              // 4 MiB
  f16* vt  = klr + (size_t)B_ * H_ * T_ * R_;              // 8 MiB
  f16* On  = vt + (size_t)B_ * H_ * T_ * D_;

  const size_t projB = (size_t)16 * 1024 * 1024;
  const size_t perSplit = (size_t)NROW * D_ * 2 + (size_t)NROW * 8;  // On + ml
  int ns_shift = 0;
  if (ws_size >= projB + 2 * perSplit) ns_shift = 1;       // NS=2
  const int NS = 1 << ns_shift;
  float2* ml = (float2*)(On + (size_t)NS * NROW * D_);

  proj_kernel<<<B_ * H_ * NT, 256, 0, stream>>>(q, k, v, Wq, Wk, c1, c2, qlr, klr, vt);
  attn_kernel<<<B_ * H_ * MT * NS, 256, 0, stream>>>(qlr, klr, vt, On, ml, ns_shift);
  merge_kernel<<<NROW / 32, 256, 0, stream>>>(On, ml, out, NS);
}

// Round 8
// 156.976 us; speedup vs baseline: 1.1012x; 1.0534x over previous
//
#include <hip/hip_runtime.h>

typedef _Float16 f16;
typedef _Float16 f16x2 __attribute__((ext_vector_type(2)));
typedef _Float16 f16x8 __attribute__((ext_vector_type(8)));
typedef float    f32x4 __attribute__((ext_vector_type(4)));
typedef float    f32x16 __attribute__((ext_vector_type(16)));
typedef unsigned int u32;

constexpr int B_ = 2, H_ = 16, T_ = 2048, D_ = 64, R_ = 32, NT = 32;

__device__ __forceinline__ f32x4 mfma16(f16x8 a, f16x8 b, f32x4 c) {
  return __builtin_amdgcn_mfma_f32_16x16x32_f16(a, b, c, 0, 0, 0);
}
__device__ __forceinline__ f32x16 mfma32(f16x8 a, f16x8 b, f32x16 c) {
  return __builtin_amdgcn_mfma_f32_32x32x16_f16(a, b, c, 0, 0, 0);
}
__device__ __forceinline__ u32 pkrtz(float a, float b) {
  return __builtin_bit_cast(u32, __builtin_amdgcn_cvt_pkrtz(a, b));
}

// Workspace layouts (all f16), fragment-order so attn frag-loads are contiguous:
//  qlr/klr: [bh][jt(32)][kc(2)][hh(2)][tl(64)][8]
//  vt:      [bh][jt(32)][u(8)][d(64)][8]

// ---------------- Kernel A: MFMA projections (unchanged R7) ----------------
__global__ __launch_bounds__(256) void proj_kernel(
    const float* __restrict__ q, const float* __restrict__ k, const float* __restrict__ v,
    const float* __restrict__ Wq, const float* __restrict__ Wk,
    const float* __restrict__ c1, const float* __restrict__ c2,
    f16* __restrict__ qlr, f16* __restrict__ klr, f16* __restrict__ vt)
{
  __shared__ f16   sv[64 * 65];
  __shared__ float sW[2][64 * 33];
  __shared__ f16   sO[2][64 * 40];

  const int tid = threadIdx.x, w = tid >> 6, lane = tid & 63;
  const int l15 = lane & 15, l4 = lane >> 4;
  const int bh = blockIdx.x >> 5, h = bh & (H_ - 1);
  const int jt = blockIdx.x & 31, t0 = jt * 64;

  const float* vb = v + ((size_t)bh * T_ + t0) * D_;
  float4 vld[4];
#pragma unroll
  for (int it = 0; it < 4; ++it) vld[it] = ((const float4*)vb)[it * 256 + tid];

  const int m = t0 + 16 * w + l15;
  const float* qr = q + ((size_t)bh * T_ + m) * D_;
  const float* kr = k + ((size_t)bh * T_ + m) * D_;
  f16x8 aq[2], ak[2];
#pragma unroll
  for (int kc = 0; kc < 2; ++kc) {
    float4 x0 = *(const float4*)(qr + kc * 32 + 8 * l4);
    float4 x1 = *(const float4*)(qr + kc * 32 + 8 * l4 + 4);
    float4 y0 = *(const float4*)(kr + kc * 32 + 8 * l4);
    float4 y1 = *(const float4*)(kr + kc * 32 + 8 * l4 + 4);
    f16x8 A, K;
    A[0]=(f16)x0.x; A[1]=(f16)x0.y; A[2]=(f16)x0.z; A[3]=(f16)x0.w;
    A[4]=(f16)x1.x; A[5]=(f16)x1.y; A[6]=(f16)x1.z; A[7]=(f16)x1.w;
    K[0]=(f16)y0.x; K[1]=(f16)y0.y; K[2]=(f16)y0.z; K[3]=(f16)y0.w;
    K[4]=(f16)y1.x; K[5]=(f16)y1.y; K[6]=(f16)y1.z; K[7]=(f16)y1.w;
    aq[kc] = A; ak[kc] = K;
  }
  const float* Wqh = Wq + (size_t)h * D_ * R_;
  const float* Wkh = Wk + (size_t)h * D_ * R_;
  float4 wq0 = ((const float4*)Wqh)[tid * 2], wq1 = ((const float4*)Wqh)[tid * 2 + 1];
  float4 wk0 = ((const float4*)Wkh)[tid * 2], wk1 = ((const float4*)Wkh)[tid * 2 + 1];

#pragma unroll
  for (int it = 0; it < 4; ++it) {
    const int i4 = it * 256 + tid, t = i4 >> 4, dq = (i4 & 15) * 4;
    sv[t * 65 + dq    ] = (f16)vld[it].x;
    sv[t * 65 + dq + 1] = (f16)vld[it].y;
    sv[t * 65 + dq + 2] = (f16)vld[it].z;
    sv[t * 65 + dq + 3] = (f16)vld[it].w;
  }
  {
    const int d = tid >> 2, r0 = (tid & 3) * 8;
    float* pq = &sW[0][d * 33 + r0];
    float* pk = &sW[1][d * 33 + r0];
    pq[0]=wq0.x; pq[1]=wq0.y; pq[2]=wq0.z; pq[3]=wq0.w;
    pq[4]=wq1.x; pq[5]=wq1.y; pq[6]=wq1.z; pq[7]=wq1.w;
    pk[0]=wk0.x; pk[1]=wk0.y; pk[2]=wk0.z; pk[3]=wk0.w;
    pk[4]=wk1.x; pk[5]=wk1.y; pk[6]=wk1.z; pk[7]=wk1.w;
  }
  __syncthreads();

  const f32x4 z4 = {0.f, 0.f, 0.f, 0.f};
#pragma unroll
  for (int nt = 0; nt < 2; ++nt) {
    const int r = 16 * nt + l15;
    f16x8 bq[2], bk[2];
#pragma unroll
    for (int kc = 0; kc < 2; ++kc)
#pragma unroll
      for (int j2 = 0; j2 < 8; ++j2) {
        const int d = kc * 32 + 8 * l4 + j2;
        bq[kc][j2] = (f16)sW[0][d * 33 + r];
        bk[kc][j2] = (f16)sW[1][d * 33 + r];
      }
    f32x4 accq = mfma16(aq[0], bq[0], z4); accq = mfma16(aq[1], bq[1], accq);
    f32x4 acck = mfma16(ak[0], bk[0], z4); acck = mfma16(ak[1], bk[1], acck);
    const float scl = c1[h * 4 + (r >> 3)] * c2[h * 8 + (r & 7)] *
                      (0.17677669529663687f * 1.4426950408889634f);
#pragma unroll
    for (int i = 0; i < 4; ++i) {
      const int row = 16 * w + 4 * l4 + i;
      sO[0][row * 40 + r] = (f16)(accq[i] * scl);
      sO[1][row * 40 + r] = (f16)acck[i];
    }
  }
  __syncthreads();

  {
    const int row = tid >> 2, q4 = tid & 3;
    const size_t base = ((((size_t)bh * 32 + jt) * 2 + (q4 >> 1)) * 2 + (q4 & 1)) * 64 + row;
    *(f16x8*)(qlr + base * 8) = *(const f16x8*)&sO[0][row * 40 + q4 * 8];
    *(f16x8*)(klr + base * 8) = *(const f16x8*)&sO[1][row * 40 + q4 * 8];
  }
#pragma unroll
  for (int it = 0; it < 8; ++it) {
    const int d = tid >> 2, i2 = (tid & 3) * 2, t = it * 8 + i2;
    f16x2 pr; pr[0] = sv[t * 65 + d]; pr[1] = sv[(t + 1) * 65 + d];
    *(f16x2*)(vt + (((size_t)bh * 32 + jt) * 8 + it) * 512 + d * 8 + i2) = pr;
  }
}

// ---------------- Kernel B: flash attention, in-block n-split + LDS merge ----------------
// Block = 64 m-rows of one (b,h). 4 waves: wave w = (m-half hw = w>>1) x (n-parity p = w&1).
// Each wave: independent barrier-free online-softmax loop over chunks j = p, p+2, .. q.
// Epilogue: parity pairs merge unnormalized fp32 partials through LDS; direct fp32 out.
__global__ __launch_bounds__(256, 4) void attn_kernel(
    const f16* __restrict__ qlr, const f16* __restrict__ klr,
    const f16* __restrict__ vt, float* __restrict__ out)
{
  __shared__ __align__(16) float  s_o[4][32 * 68];   // 34.8 KB, epilogue only
  __shared__ float2 s_ml[4][32];

  const int tid = threadIdx.x, w = tid >> 6, lane = tid & 63;
  const int l31 = lane & 31, hh = lane >> 5;
  const int p = w & 1, hw = w >> 1;
  const int bh = blockIdx.x & 31;
  const int qt = 31 - (blockIdx.x >> 5);   // longest rows dispatch first
  const int m0 = qt * 64;
  const int mw = m0 + 32 * hw;

  // persistent Q B-frags: B[k=r][col=m=l31]
  const int mloc = 32 * hw + l31;
  const f16* qb = qlr + (((size_t)bh * 32 + qt) * 2048) + hh * 512 + (size_t)mloc * 8;
  const f16x8 bq0 = *(const f16x8*)(qb);
  const f16x8 bq1 = *(const f16x8*)(qb + 1024);

  const f16* kb = klr + (size_t)bh * 32 * 2048;
  const f16* vb = vt + (size_t)bh * 32 * 4096;

  f32x16 oacc[2];
  f32x16 z16;
#pragma unroll
  for (int e = 0; e < 16; ++e) { z16[e] = 0.f; oacc[0][e] = 0.f; oacc[1][e] = 0.f; }
  float mi = -1e30f, li = 0.f;

  for (int j = p; j <= qt; j += 2) {
    const f16* kj = kb + (size_t)j * 2048;
    const f16* vj = vb + (size_t)j * 4096;

    // ---- S^T[n][m] ----
    f32x16 sc[2];
#pragma unroll
    for (int nt = 0; nt < 2; ++nt) {
      const int nl = 32 * nt + l31;
      const f16x8 a0 = *(const f16x8*)(kj + hh * 512 + nl * 8);
      const f16x8 a1 = *(const f16x8*)(kj + 1024 + hh * 512 + nl * 8);
      sc[nt] = mfma32(a0, bq0, z16);
      sc[nt] = mfma32(a1, bq1, sc[nt]);
    }
    // causal mask: only this wave's last chunk straddles its rows
    const int n0 = j * 64;
    if (n0 + 63 > mw) {
      const int lim = mw + l31 - n0;
#pragma unroll
      for (int nt = 0; nt < 2; ++nt)
#pragma unroll
        for (int e = 0; e < 16; ++e) {
          const int nv = 32 * nt + 4 * hh + (e & 3) + 8 * (e >> 2);
          if (nv > lim) sc[nt][e] = -1e30f;
        }
    }

    // ---- online softmax (scalar state per lane; halves combined via 1 shfl) ----
    float rm = -1e30f;
#pragma unroll
    for (int nt = 0; nt < 2; ++nt)
#pragma unroll
      for (int e = 0; e < 16; ++e) rm = fmaxf(rm, sc[nt][e]);
    rm = fmaxf(rm, __shfl_xor(rm, 32));
    const float mn = fmaxf(mi, rm);
    const float alpha = exp2f(mi - mn);
    float rs = 0.f;
    u32 pk[2][8];
#pragma unroll
    for (int nt = 0; nt < 2; ++nt)
#pragma unroll
      for (int s4 = 0; s4 < 4; ++s4) {
        const float p0 = exp2f(sc[nt][4 * s4 + 0] - mn);
        const float p1 = exp2f(sc[nt][4 * s4 + 1] - mn);
        const float p2 = exp2f(sc[nt][4 * s4 + 2] - mn);
        const float p3 = exp2f(sc[nt][4 * s4 + 3] - mn);
        rs += (p0 + p1) + (p2 + p3);
        pk[nt][2 * s4]     = pkrtz(p0, p1);
        pk[nt][2 * s4 + 1] = pkrtz(p2, p3);
      }
    rs += __shfl_xor(rs, 32);
    li = li * alpha + rs; mi = mn;
#pragma unroll
    for (int c = 0; c < 2; ++c)
#pragma unroll
      for (int e = 0; e < 16; ++e) oacc[c][e] *= alpha;

    // ---- PV: in-register P transpose (quad swap lane^32) + mfma32 ----
#pragma unroll
    for (int nt = 0; nt < 2; ++nt)
#pragma unroll
      for (int kcp = 0; kcp < 2; ++kcp) {
        const int kc = 2 * nt + kcp;
        const u32 sA = hh ? pk[nt][4 * kcp]     : pk[nt][4 * kcp + 2];
        const u32 sB = hh ? pk[nt][4 * kcp + 1] : pk[nt][4 * kcp + 3];
        const u32 kA = hh ? pk[nt][4 * kcp + 2] : pk[nt][4 * kcp];
        const u32 kB = hh ? pk[nt][4 * kcp + 3] : pk[nt][4 * kcp + 1];
        const u32 r0 = (u32)__shfl_xor((int)sA, 32);
        const u32 r1 = (u32)__shfl_xor((int)sB, 32);
        union { f16x8 v; u32 u[4]; } bp;
        bp.u[0] = hh ? r0 : kA;
        bp.u[1] = hh ? r1 : kB;
        bp.u[2] = hh ? kA : r0;
        bp.u[3] = hh ? kB : r1;
#pragma unroll
        for (int c = 0; c < 2; ++c) {
          const f16x8 av = *(const f16x8*)(vj + (size_t)(kc * 2 + hh) * 512 + (32 * c + l31) * 8);
          oacc[c] = mfma32(av, bp.v, oacc[c]);
        }
      }
  }

  // ---- epilogue: unnormalized partials -> LDS ----
#pragma unroll
  for (int c = 0; c < 2; ++c)
#pragma unroll
    for (int s4 = 0; s4 < 4; ++s4) {
      f32x4 ov;
#pragma unroll
      for (int e = 0; e < 4; ++e) ov[e] = oacc[c][4 * s4 + e];
      *(f32x4*)&s_o[w][l31 * 68 + 32 * c + 8 * s4 + 4 * hh] = ov;
    }
  if (!hh) {
    float2 mlv; mlv.x = mi; mlv.y = li;
    s_ml[w][l31] = mlv;
  }
  __syncthreads();

  // ---- merge parity pairs, write fp32 out coalesced ----
  {
    const int mrow = tid >> 2;            // 0..63 block-local m
    const int d0 = (tid & 3) * 16;
    const int wA = (mrow >> 5) * 2, wB = wA + 1, ml = mrow & 31;
    const float2 a = s_ml[wA][ml], b = s_ml[wB][ml];
    const float ms = fmaxf(a.x, b.x);
    const float eA = exp2f(a.x - ms), eB = exp2f(b.x - ms);
    const float inv = 1.f / (eA * a.y + eB * b.y);
    const float cA = eA * inv, cB = eB * inv;
    float* ob = out + ((size_t)bh * T_ + m0 + mrow) * D_ + d0;
#pragma unroll
    for (int seg = 0; seg < 4; ++seg) {
      const f32x4 oA = *(const f32x4*)&s_o[wA][ml * 68 + d0 + 4 * seg];
      const f32x4 oB = *(const f32x4*)&s_o[wB][ml * 68 + d0 + 4 * seg];
      f32x4 r;
#pragma unroll
      for (int e = 0; e < 4; ++e) r[e] = cA * oA[e] + cB * oB[e];
      *(f32x4*)(ob + 4 * seg) = r;
    }
  }
}

extern "C" void kernel_launch(void* const* d_in, const int* in_sizes, int n_in,
                              void* d_out, int out_size, void* d_ws, size_t ws_size,
                              hipStream_t stream) {
  const float* q  = (const float*)d_in[0];
  const float* k  = (const float*)d_in[1];
  const float* v  = (const float*)d_in[2];
  const float* Wq = (const float*)d_in[3];
  const float* Wk = (const float*)d_in[4];
  const float* c1 = (const float*)d_in[5];
  const float* c2 = (const float*)d_in[6];
  float* out = (float*)d_out;

  f16* qlr = (f16*)d_ws;                                   // 4 MiB
  f16* klr = qlr + (size_t)B_ * H_ * T_ * R_;              // 4 MiB
  f16* vt  = klr + (size_t)B_ * H_ * T_ * R_;              // 8 MiB

  proj_kernel<<<B_ * H_ * NT, 256, 0, stream>>>(q, k, v, Wq, Wk, c1, c2, qlr, klr, vt);
  attn_kernel<<<B_ * H_ * NT, 256, 0, stream>>>(qlr, klr, vt, out);
}